// Round 11
// baseline (327.109 us; speedup 1.0000x reference)
//
#include <hip/hip_runtime.h>
#include <hip/hip_fp16.h>

#define N_NODES 50000
#define N_EDGES 400000
#define CSR_E (2 * N_EDGES + N_NODES) /* 850000 */
#define NCH 10        /* source chunks */
#define CHW 5000      /* chunk width: 5000 nodes * 256B = 1.28MB window */
#define NE2 (N_NODES * NCH) /* buckets: (node, chunk), node-major contiguous */

typedef unsigned short ushort_t;
typedef unsigned int uint_t;
typedef __attribute__((ext_vector_type(8))) short bf16x8;
typedef __attribute__((ext_vector_type(4))) float f32x4;

__device__ __forceinline__ float bf2f(ushort_t u) {
    return __uint_as_float(((uint_t)u) << 16);
}
__device__ __forceinline__ ushort_t f2bf(float f) {
    uint_t b = __float_as_uint(f);
    b += 0x7FFFu + ((b >> 16) & 1u); // RNE
    return (ushort_t)(b >> 16);
}
// fp16 pair packing for CSR entry weights (low = S-channel, high = D-channel)
__device__ __forceinline__ uint_t packw(float a, float b) {
    return ((uint_t)__half_as_ushort(__float2half(b)) << 16) |
           (uint_t)__half_as_ushort(__float2half(a));
}
__device__ __forceinline__ float unpl(uint_t w) {
    return __half2float(__ushort_as_half((ushort_t)(w & 0xffffu)));
}
__device__ __forceinline__ float unph(uint_t w) {
    return __half2float(__ushort_as_half((ushort_t)(w >> 16)));
}

// ---------------- static device scratch (module BSS; d_ws untouched) ----------------
// NOTE: only reference these from device code (host sees shadow addresses - r4 fault).

__device__ int g_est;  // edge-index word stride: 1 = int32, 2 = int64
__device__ int g_is16; // 1 = float tensors bf16-packed, 0 = fp32
__device__ __align__(8) float2 g_dis2[N_NODES]; // (dis_s, dis_r)
__device__ int g_cnt2[NE2];
__device__ int g_offs2[NE2 + 1];
__device__ uint_t g_rank[N_EDGES]; // low16 = fwd rank, high16 = rev rank
__device__ int g_bsum[512];
__device__ int g_bbase[512];
__device__ __align__(16) uint2 g_csr8[CSR_E]; // {src, half2 w}: raw (out,in) -> final src-folded
__device__ __align__(16) ushort_t g_h1[(size_t)N_NODES * 128];  // bf16
__device__ __align__(16) ushort_t g_xcvt[(size_t)N_NODES * 128]; // bf16 (fp32-input fallback)
__device__ __align__(16) ushort_t g_bp1[8 * 128 * 32]; // B packed [kb][n][kk] bf16
__device__ __align__(16) ushort_t g_bp2[8 * 128 * 32];
__device__ __align__(16) ushort_t g_bp3[4 * 64 * 32];
__device__ float g_bc1[128];
__device__ float g_bc2[128];
__device__ float g_bro[64];

// ---------------- detection + count init (merged) ----------------

__global__ __launch_bounds__(256) void init_detect(const uint_t* __restrict__ xw,
                                                   const int* __restrict__ eidx) {
    int n = blockIdx.x * 256 + threadIdx.x;
    if (n == 0) {
        int cnt = 0;
        for (int i = 0; i < 64; i++) {
            uint_t w = xw[i];
            int elo = (w >> 7) & 0xFF;
            if (elo >= 100 && elo <= 150) cnt++;
        }
        g_is16 = (cnt >= 48) ? 1 : 0;
        int any = 0;
        for (int i = 1; i < 128; i += 2) any |= eidx[i];
        g_est = any ? 1 : 2;
    }
    if (n < N_NODES) {
        int sc = n / CHW;
#pragma unroll
        for (int c = 0; c < NCH; c++) g_cnt2[n * NCH + c] = (c == sc) ? 1 : 0; // self-loop slot
    }
}

// fp32-input fallback: convert x to bf16 once (no-op when already bf16)
__global__ __launch_bounds__(256) void conv_x(const float* __restrict__ x32) {
    if (g_is16) return;
    int t = blockIdx.x * 256 + threadIdx.x;
    if (t >= N_NODES * 128 / 8) return;
    const float4* p = (const float4*)(x32 + t * 8);
    float4 a = p[0], b = p[1];
    ushort4 o0, o1;
    o0.x = f2bf(a.x); o0.y = f2bf(a.y); o0.z = f2bf(a.z); o0.w = f2bf(a.w);
    o1.x = f2bf(b.x); o1.y = f2bf(b.y); o1.z = f2bf(b.z); o1.w = f2bf(b.w);
    *(ushort4*)(g_xcvt + t * 8) = o0;
    *(ushort4*)(g_xcvt + t * 8 + 4) = o1;
}

// ---------------- edge counting; atomicAdd return value IS the bucket rank ----------------

__global__ __launch_bounds__(256) void edge_cnt(const int* __restrict__ eidx) {
    int e = blockIdx.x * 256 + threadIdx.x;
    if (e >= N_EDGES) return;
    int st = g_est;
    int s = eidx[(size_t)e * st];
    int r = eidx[((size_t)N_EDGES + e) * st];
    int rf = atomicAdd(&g_cnt2[r * NCH + s / CHW], 1); // fwd: dst=r, chunk of s
    int rr = atomicAdd(&g_cnt2[s * NCH + r / CHW], 1); // rev: dst=s, chunk of r
    g_rank[e] = (uint_t)rf | ((uint_t)rr << 16);       // ranks < 65536 (max degree ~100)
}

// ---------------- exclusive scan over NE2 counts ----------------

__global__ __launch_bounds__(1024) void scan1() {
    __shared__ int sd[1024];
    int i = blockIdx.x * 1024 + threadIdx.x;
    int v = (i < NE2) ? g_cnt2[i] : 0;
    sd[threadIdx.x] = v;
    __syncthreads();
    for (int o = 1; o < 1024; o <<= 1) {
        int tv = (threadIdx.x >= o) ? sd[threadIdx.x - o] : 0;
        __syncthreads();
        sd[threadIdx.x] += tv;
        __syncthreads();
    }
    if (i < NE2) g_offs2[i] = sd[threadIdx.x] - v;
    if (threadIdx.x == 1023) g_bsum[blockIdx.x] = sd[1023];
}

__global__ __launch_bounds__(512) void scan2(int nb) { // one block, parallel
    __shared__ int sd[512];
    int i = threadIdx.x;
    int v = (i < nb) ? g_bsum[i] : 0;
    sd[i] = v;
    __syncthreads();
    for (int o = 1; o < 512; o <<= 1) {
        int t = (i >= o) ? sd[i - o] : 0;
        __syncthreads();
        sd[i] += t;
        __syncthreads();
    }
    if (i < nb) g_bbase[i] = sd[i] - v;
    if (i == 0) g_offs2[NE2] = CSR_E; // sentinel
}

__global__ __launch_bounds__(256) void scan3() {
    int i = blockIdx.x * 256 + threadIdx.x;
    if (i < NE2) g_offs2[i] = g_offs2[i] + g_bbase[i >> 10];
}

// ---------------- CSR fill: ZERO atomics (rank + offs2), 8B entries ----------------

__global__ __launch_bounds__(256) void fill_all(const int* __restrict__ eidx,
                                                const ushort_t* __restrict__ th16,
                                                const float* __restrict__ th32) {
    int e = blockIdx.x * 256 + threadIdx.x;
    if (e < N_EDGES) {
        int st = g_est;
        int s = eidx[(size_t)e * st];
        int r = eidx[((size_t)N_EDGES + e) * st];
        float t = g_is16 ? bf2f(th16[e]) : th32[e];
        float sn, cs_;
        sincosf(t, &sn, &cs_);
        float c2 = cs_ * cs_;
        float s2 = sn * sn;
        uint_t rk = g_rank[e];
        int pf = g_offs2[r * NCH + s / CHW] + (int)(rk & 0xffffu);
        int pr = g_offs2[s * NCH + r / CHW] + (int)(rk >> 16);
        g_csr8[pf] = make_uint2((uint_t)s, packw(c2, s2)); // fwd: cs=s, out=c2, in=s2
        g_csr8[pr] = make_uint2((uint_t)r, packw(s2, c2)); // rev: cs=r, out=s2, in=c2
    }
    if (e < N_NODES) { // self-loop at rank 0 of its bucket
        int p = g_offs2[e * NCH + e / CHW];
        g_csr8[p] = make_uint2((uint_t)e, packw(1.0f, 1.0f));
    }
}

// ---------------- degrees (atomic-free; pairing identity) ----------------
// deg_s[n] = sum of in_w over node-n entries; deg_r[n] = sum of out_w.

__global__ __launch_bounds__(256) void deg_pass() {
    int n = blockIdx.x * 256 + threadIdx.x;
    if (n >= N_NODES) return;
    int kb = g_offs2[n * NCH];
    int ke = g_offs2[n * NCH + NCH];
    float ds = 0.f, dr = 0.f;
    for (int k = kb; k < ke; k++) {
        uint_t w = g_csr8[k].y;
        ds += unph(w); // in_w
        dr += unpl(w); // out_w
    }
    g_dis2[n] = make_float2(rsqrtf(ds + 1e-12f), rsqrtf(dr + 1e-12f));
}

// ---------------- finalize: fold SRC factors only (dst folded in agg epilogue) ----------------

__global__ __launch_bounds__(256) void finalize_w() {
    int i = blockIdx.x * 256 + threadIdx.x;
    if (i >= CSR_E) return;
    uint2 e = g_csr8[i];
    float2 d = g_dis2[e.x]; // (dis_s, dis_r) of src
    ((uint_t*)g_csr8)[2 * (size_t)i + 1] = packw(d.x * unpl(e.y), d.y * unph(e.y));
}

// ---------------- weight prep (merged): Bp[kb][n][kk] bf16 + biases ----------------

__global__ __launch_bounds__(256) void prep_all(const ushort_t* W1s16, const float* W1s32,
                                                const ushort_t* W1d16, const float* W1d32,
                                                const ushort_t* b1s16, const float* b1s32,
                                                const ushort_t* b1d16, const float* b1d32,
                                                const ushort_t* W2s16, const float* W2s32,
                                                const ushort_t* W2d16, const float* W2d32,
                                                const ushort_t* b2s16, const float* b2s32,
                                                const ushort_t* b2d16, const float* b2d32,
                                                const ushort_t* Wro16, const float* Wro32,
                                                const ushort_t* bro16, const float* bro32) {
    int is16 = g_is16;
    int t = blockIdx.x * 256 + threadIdx.x;
    if (t < 2 * 32768) { // hidden layers
        int layer = t >> 15;
        int i = t & 32767;
        const ushort_t* Ws16 = layer ? W2s16 : W1s16;
        const float* Ws32 = layer ? W2s32 : W1s32;
        const ushort_t* Wd16 = layer ? W2d16 : W1d16;
        const float* Wd32 = layer ? W2d32 : W1d32;
        ushort_t* Bp = layer ? g_bp2 : g_bp1;
        int k = i >> 7, n = i & 127;
        ushort_t v;
        if (k < 128) {
            int idx = k * 128 + n;
            v = is16 ? Ws16[idx] : f2bf(Ws32[idx]);
        } else {
            int idx = (k - 128) * 128 + n;
            v = is16 ? Wd16[idx] : f2bf(Wd32[idx]);
        }
        int kb = k >> 5, kk = k & 31;
        Bp[((kb * 128 + n) << 5) + kk] = v;
        if (i < 128) {
            const ushort_t* bs16 = layer ? b2s16 : b1s16;
            const float* bs32 = layer ? b2s32 : b1s32;
            const ushort_t* bd16 = layer ? b2d16 : b1d16;
            const float* bd32 = layer ? b2d32 : b1d32;
            float a = is16 ? bf2f(bs16[i]) : bs32[i];
            float b = is16 ? bf2f(bd16[i]) : bd32[i];
            (layer ? g_bc2 : g_bc1)[i] = 0.5f * (a + b);
        }
    } else if (t < 2 * 32768 + 8192) { // readout
        int i = t - 2 * 32768;
        int k = i >> 6, n = i & 63;
        ushort_t v = is16 ? Wro16[i] : f2bf(Wro32[i]);
        int kb = k >> 5, kk = k & 31;
        g_bp3[((kb * 64 + n) << 5) + kk] = v;
        if (i < 64) g_bro[i] = is16 ? bf2f(bro16[i]) : bro32[i];
    }
}

// ---------------- FUSED layer: gang-aggregate -> LDS tile -> MFMA GEMM ----------------
// LAYER 0: h1 = relu(agg(x) @ W1 + b1)           -- agg tile never touches HBM
// LAYER 1: out = (relu(agg(h1) @ W2 + b2)) @ Wro + bro  -- h2 tile transposes via LDS
// Block = 4 waves x 64 nodes. Wave w owns block-rows w*16..w*16+15 end-to-end:
// it aggregates them (gang: 4 nodes/iter, 16-lane groups, 4 entry-rows per
// gather instruction - the r9 VMEM-inst-wall fix), writes bf16 to its own LDS
// rows, then MFMAs those same rows. All LDS production/consumption is
// wave-private => NO barriers (wave lockstep + compiler lgkmcnt ordering).
// aggT row stride 264 (=256+8) and h2T stride 136 (=128+8) keep 16B alignment
// and break the power-of-2 bank alias on ds_read_b128.

template <int LAYER>
__global__ __launch_bounds__(256) void fused_layer(const ushort_t* __restrict__ xext,
                                                   void* __restrict__ outp) {
    __shared__ ushort_t aggT[64 * 264];                    // 33.8 KB
    __shared__ ushort_t h2T[(LAYER == 1) ? 64 * 136 : 1];  // 17.4 KB (L1 only)
    int w = threadIdx.x >> 6;
    int lane = threadIdx.x & 63;
    int gsel = lane >> 4; // node within quad / q for MFMA
    int r = lane & 15;    // feature sub-block / col for MFMA
    const ushort_t* xin = (LAYER == 0) ? (g_is16 ? xext : g_xcvt) : g_h1;

    // ---- stage A: aggregate 16 nodes (4 iters x 4 nodes) into LDS ----
    for (int it = 0; it < 4; it++) {
        int lrow = w * 16 + it * 4 + gsel;
        int node = blockIdx.x * 64 + lrow;
        int cn = min(node, N_NODES - 1); // clamp; garbage rows never stored
        int ks = g_offs2[cn * NCH];
        int ke = g_offs2[cn * NCH + NCH];
        int c = ke - ks;
        int cmax = c;
        cmax = max(cmax, __shfl_xor(cmax, 16));
        cmax = max(cmax, __shfl_xor(cmax, 32));

        float accS[8], accD[8];
#pragma unroll
        for (int f = 0; f < 8; f++) { accS[f] = 0.f; accD[f] = 0.f; }

        int k = 0;
        for (; k + 2 <= cmax; k += 2) {
            int i0 = ks + min(k, c - 1);
            int i1 = ks + min(k + 1, c - 1);
            uint2 e0 = g_csr8[i0];
            uint2 e1 = g_csr8[i1];
            bf16x8 v0 = *(const bf16x8*)(xin + (size_t)e0.x * 128 + r * 8);
            bf16x8 v1 = *(const bf16x8*)(xin + (size_t)e1.x * 128 + r * 8);
            float w0s = (k < c) ? unpl(e0.y) : 0.f;
            float w0d = (k < c) ? unph(e0.y) : 0.f;
            float w1s = (k + 1 < c) ? unpl(e1.y) : 0.f;
            float w1d = (k + 1 < c) ? unph(e1.y) : 0.f;
#pragma unroll
            for (int f = 0; f < 8; f++) {
                float x0 = bf2f((ushort_t)v0[f]);
                float x1 = bf2f((ushort_t)v1[f]);
                accS[f] = fmaf(w0s, x0, accS[f]);
                accD[f] = fmaf(w0d, x0, accD[f]);
                accS[f] = fmaf(w1s, x1, accS[f]);
                accD[f] = fmaf(w1d, x1, accD[f]);
            }
        }
        if (k < cmax) {
            int i0 = ks + min(k, c - 1);
            uint2 e0 = g_csr8[i0];
            bf16x8 v0 = *(const bf16x8*)(xin + (size_t)e0.x * 128 + r * 8);
            float w0s = (k < c) ? unpl(e0.y) : 0.f;
            float w0d = (k < c) ? unph(e0.y) : 0.f;
#pragma unroll
            for (int f = 0; f < 8; f++) {
                float x0 = bf2f((ushort_t)v0[f]);
                accS[f] = fmaf(w0s, x0, accS[f]);
                accD[f] = fmaf(w0d, x0, accD[f]);
            }
        }

        float2 dn = g_dis2[cn];
        float fs = 0.5f * dn.y; // S: 0.5 * dis_r[dst]
        float fd = 0.5f * dn.x; // D: 0.5 * dis_s[dst]
        uint_t oS[4], oD[4];
#pragma unroll
        for (int p = 0; p < 4; p++) {
            oS[p] = ((uint_t)f2bf(accS[2 * p + 1] * fs) << 16) | (uint_t)f2bf(accS[2 * p] * fs);
            oD[p] = ((uint_t)f2bf(accD[2 * p + 1] * fd) << 16) | (uint_t)f2bf(accD[2 * p] * fd);
        }
        *(uint4*)(&aggT[lrow * 264 + r * 8]) = make_uint4(oS[0], oS[1], oS[2], oS[3]);
        *(uint4*)(&aggT[lrow * 264 + 128 + r * 8]) = make_uint4(oD[0], oD[1], oD[2], oD[3]);
    }

    // ---- stage B: MFMA GEMM over this wave's 16 LDS rows (K=256, N=128) ----
    // A[m=lane&15][k=(lane>>4)*8+j]; B[k][n=lane&15]; C col=lane&15,row=(lane>>4)*4+reg.
    const ushort_t* Bp = LAYER ? g_bp2 : g_bp1;
    const float* bias = LAYER ? g_bc2 : g_bc1;
    int q = gsel;
    f32x4 acc[8];
#pragma unroll
    for (int nt = 0; nt < 8; nt++) acc[nt] = {0.f, 0.f, 0.f, 0.f};
#pragma unroll
    for (int kb = 0; kb < 8; kb++) {
        bf16x8 a = *(const bf16x8*)(&aggT[(w * 16 + r) * 264 + kb * 32 + q * 8]);
#pragma unroll
        for (int nt = 0; nt < 8; nt++) {
            bf16x8 b = *(const bf16x8*)(Bp + (((kb * 128 + nt * 16 + r) << 5) + q * 8));
            acc[nt] = __builtin_amdgcn_mfma_f32_16x16x32_bf16(a, b, acc[nt], 0, 0, 0);
        }
    }

#pragma unroll
    for (int nt = 0; nt < 8; nt++) {
        int n = nt * 16 + r;
        float bi = bias[n];
#pragma unroll
        for (int rr = 0; rr < 4; rr++) {
            float v = fmaxf(acc[nt][rr] + bi, 0.f);
            if (LAYER == 0) {
                int m = blockIdx.x * 64 + w * 16 + q * 4 + rr;
                if (m < N_NODES) g_h1[(size_t)m * 128 + n] = f2bf(v);
            } else {
                h2T[(w * 16 + q * 4 + rr) * 136 + n] = f2bf(v); // C-layout -> LDS transpose
            }
        }
    }

    // ---- stage C (LAYER 1 only): readout MFMA (K=128, N=64) from h2T ----
    if (LAYER == 1) {
        f32x4 acc2[4];
#pragma unroll
        for (int nt = 0; nt < 4; nt++) acc2[nt] = {0.f, 0.f, 0.f, 0.f};
#pragma unroll
        for (int kb = 0; kb < 4; kb++) {
            bf16x8 a = *(const bf16x8*)(&h2T[(w * 16 + r) * 136 + kb * 32 + q * 8]);
#pragma unroll
            for (int nt = 0; nt < 4; nt++) {
                bf16x8 b = *(const bf16x8*)(g_bp3 + (((kb * 64 + nt * 16 + r) << 5) + q * 8));
                acc2[nt] = __builtin_amdgcn_mfma_f32_16x16x32_bf16(a, b, acc2[nt], 0, 0, 0);
            }
        }
        int is16 = g_is16;
#pragma unroll
        for (int nt = 0; nt < 4; nt++) {
            int n = nt * 16 + r;
            float bi = g_bro[n];
#pragma unroll
            for (int rr = 0; rr < 4; rr++) {
                int m = blockIdx.x * 64 + w * 16 + q * 4 + rr;
                if (m >= N_NODES) continue;
                float v = acc2[nt][rr] + bi;
                if (is16)
                    ((ushort_t*)outp)[(size_t)m * 64 + n] = f2bf(v);
                else
                    ((float*)outp)[(size_t)m * 64 + n] = v;
            }
        }
    }
}

// ---------------- launch ----------------

static inline int cdiv(int a, int b) { return (a + b - 1) / b; }

extern "C" void kernel_launch(void* const* d_in, const int* in_sizes, int n_in,
                              void* d_out, int out_size, void* d_ws, size_t ws_size,
                              hipStream_t stream) {
    const void* x = d_in[0]; // [50000][128]
    const int* eidx = (const int*)d_in[1];
    const void* theta = d_in[2];
    const void* W1s = d_in[3];
    const void* W1d = d_in[4];
    const void* b1s = d_in[5];
    const void* b1d = d_in[6];
    const void* W2s = d_in[7];
    const void* W2d = d_in[8];
    const void* b2s = d_in[9];
    const void* b2d = d_in[10];
    const void* Wro = d_in[11];
    const void* bro = d_in[12];
    (void)in_sizes; (void)n_in; (void)out_size; (void)d_ws; (void)ws_size;

    const int NB2 = cdiv(NE2, 1024); // 489

    init_detect<<<cdiv(N_NODES, 256), 256, 0, stream>>>((const uint_t*)x, eidx);
    conv_x<<<cdiv(N_NODES * 128 / 8, 256), 256, 0, stream>>>((const float*)x);
    edge_cnt<<<cdiv(N_EDGES, 256), 256, 0, stream>>>(eidx);
    scan1<<<NB2, 1024, 0, stream>>>();
    scan2<<<1, 512, 0, stream>>>(NB2);
    scan3<<<cdiv(NE2, 256), 256, 0, stream>>>();
    fill_all<<<cdiv(N_EDGES, 256), 256, 0, stream>>>(eidx, (const ushort_t*)theta, (const float*)theta);
    deg_pass<<<cdiv(N_NODES, 256), 256, 0, stream>>>();
    finalize_w<<<cdiv(CSR_E, 256), 256, 0, stream>>>();
    prep_all<<<cdiv(2 * 32768 + 8192, 256), 256, 0, stream>>>(
        (const ushort_t*)W1s, (const float*)W1s, (const ushort_t*)W1d, (const float*)W1d,
        (const ushort_t*)b1s, (const float*)b1s, (const ushort_t*)b1d, (const float*)b1d,
        (const ushort_t*)W2s, (const float*)W2s, (const ushort_t*)W2d, (const float*)W2d,
        (const ushort_t*)b2s, (const float*)b2s, (const ushort_t*)b2d, (const float*)b2d,
        (const ushort_t*)Wro, (const float*)Wro, (const ushort_t*)bro, (const float*)bro);

    const int FB = cdiv(N_NODES, 64); // 782 blocks, 64 nodes each
    fused_layer<0><<<FB, 256, 0, stream>>>((const ushort_t*)x, nullptr);
    fused_layer<1><<<FB, 256, 0, stream>>>(nullptr, d_out);
}